// Round 3
// baseline (423.645 us; speedup 1.0000x reference)
//
#include <hip/hip_runtime.h>
#include <math.h>

// Problem constants (B=1)
// N=512, CS=384, CZ=128, G=16, CH=48, H=8, PQ=8, PV=12, NF=4, CZ4=32
// feats dim = 384 (o) + 96*3 (o_pt xyz) + 96 (norm) + 256 (o_pair) = 1024

// ---- workspace layout (floats) ----
#define OFF_PROJ 0
#define SZ_PROJ (512*1632)
#define OFF_QW (OFF_PROJ + SZ_PROJ)
#define SZ_QW (8*512*192)
#define OFF_KST (OFF_QW + SZ_QW)
#define OFF_V (OFF_KST + SZ_QW)
#define SZ_V (512*384)
#define OFF_VP (OFF_V + SZ_V)
#define SZ_VP (512*288)
#define OFF_A (OFF_VP + SZ_VP)
#define SZ_A (8*512*512)
#define OFF_FEATS (OFF_A + SZ_A)
#define SZ_FEATS (512*1024)
#define OFF_PART (OFF_FEATS + SZ_FEATS)
#define SZ_PART (8*512*384)

// ============ K1: s @ [wq|wkv|wkvp] + bias -> proj (512 x 1632) ============
__global__ __launch_bounds__(256) void proj_kernel(
    const float* __restrict__ s, const float* __restrict__ wq, const float* __restrict__ bq,
    const float* __restrict__ wkv, const float* __restrict__ bkv,
    const float* __restrict__ wkvp, const float* __restrict__ bkvp,
    float* __restrict__ proj)
{
  __shared__ float sT[384][34];
  int ct = blockIdx.x;          // 26 col tiles of 64
  int i0 = blockIdx.y * 32;
  int col0 = ct * 64;
  const float* W; const float* bias; int wld, wcol0;
  if (col0 < 384)       { W = wq;   bias = bq;   wld = 384; wcol0 = col0; }
  else if (col0 < 1152) { W = wkv;  bias = bkv;  wld = 768; wcol0 = col0 - 384; }
  else                  { W = wkvp; bias = bkvp; wld = 480; wcol0 = col0 - 1152; }
  int t = threadIdx.x;
  #pragma unroll
  for (int r = 0; r < 12; r++){
    int e = t + 256*r;
    int i = e & 31;
    int k4 = e >> 5;            // 0..95
    float4 v = *(const float4*)(s + (size_t)(i0 + i)*384 + k4*4);
    sT[k4*4+0][i] = v.x; sT[k4*4+1][i] = v.y; sT[k4*4+2][i] = v.z; sT[k4*4+3][i] = v.w;
  }
  __syncthreads();
  int cr = t & 15;
  int ipair = t >> 4;
  int ii = ipair * 2;
  int wc = wcol0 + cr*4;
  bool valid = (wc + 4 <= wld);
  int wcc = valid ? wc : (wld - 4);
  float acc[2][4];
  #pragma unroll
  for (int q = 0; q < 2; q++)
    #pragma unroll
    for (int p = 0; p < 4; p++) acc[q][p] = 0.f;
  #pragma unroll 4
  for (int k = 0; k < 384; k++){
    float2 a2 = *(const float2*)&sT[k][ii];
    float4 w4 = *(const float4*)(W + (size_t)k*wld + wcc);
    acc[0][0] = fmaf(a2.x, w4.x, acc[0][0]);
    acc[0][1] = fmaf(a2.x, w4.y, acc[0][1]);
    acc[0][2] = fmaf(a2.x, w4.z, acc[0][2]);
    acc[0][3] = fmaf(a2.x, w4.w, acc[0][3]);
    acc[1][0] = fmaf(a2.y, w4.x, acc[1][0]);
    acc[1][1] = fmaf(a2.y, w4.y, acc[1][1]);
    acc[1][2] = fmaf(a2.y, w4.z, acc[1][2]);
    acc[1][3] = fmaf(a2.y, w4.w, acc[1][3]);
  }
  if (valid){
    float4 bv = *(const float4*)(bias + wc);
    #pragma unroll
    for (int q = 0; q < 2; q++){
      int row = i0 + ii + q;
      float4 o;
      o.x = acc[q][0] + bv.x; o.y = acc[q][1] + bv.y;
      o.z = acc[q][2] + bv.z; o.w = acc[q][3] + bv.w;
      *(float4*)(proj + (size_t)row*1632 + col0 + cr*4) = o;
    }
  }
}

// ============ K2: per-node rotation + pack Qw/Kst (192-d), V, VP ============
__global__ __launch_bounds__(128) void node_kernel(
    const float* __restrict__ proj, const float* __restrict__ rotvec,
    const float* __restrict__ lfa, const float* __restrict__ gwts, const float* __restrict__ fwts,
    float* __restrict__ Qw, float* __restrict__ Kst, float* __restrict__ V, float* __restrict__ VP)
{
  int i = blockIdx.x, t = threadIdx.x;
  const float* pr = proj + (size_t)i*1632;
  float rx = rotvec[i*3], ry = rotvec[i*3+1], rz = rotvec[i*3+2];
  float nrm = sqrtf(rx*rx + ry*ry + rz*rz);
  float angle = nrm + 1e-8f;
  float inv = 1.0f / fmaxf(nrm, 1e-12f);
  float ax = rx*inv, ay = ry*inv, az = rz*inv;
  float f0 = fwts[0], f1 = fwts[1], f2 = fwts[2], f3 = fwts[3];
  float mfw = fmaxf(fmaxf(f0,f1), fmaxf(f2,f3));
  float e0 = expf(f0-mfw), e1 = expf(f1-mfw), e2 = expf(f2-mfw), e3 = expf(f3-mfw);
  float esum = e0+e1+e2+e3;
  float fw[4] = {e0/esum, e1/esum, e2/esum, e3/esum};
  float fq[4] = { 1.0f*expf(lfa[0]), 0.35355339059327373f*expf(lfa[1]),
                  0.125f*expf(lfa[2]), 0.04419417382415922f*expf(lfa[3]) };
  int h = t >> 4, g = t & 15;
  float gw = log1pf(expf(gwts[g])) * 0.25f;
  float q0 = pr[h*48 + g*3 + 0], q1 = pr[h*48 + g*3 + 1], q2 = pr[h*48 + g*3 + 2];
  float k0 = pr[384 + h*96 + g*3 + 0], k1 = pr[384 + h*96 + g*3 + 1], k2 = pr[384 + h*96 + g*3 + 2];
  #pragma unroll
  for (int f = 0; f < 4; f++){
    float th = angle * fq[f];
    float sn = sinf(th), cs = cosf(th), omc = 1.0f - cs;
    float r00 = cs + omc*ax*ax,       r01 = omc*ax*ay - sn*az,  r02 = omc*ax*az + sn*ay;
    float r10 = omc*ay*ax + sn*az,    r11 = cs + omc*ay*ay,     r12 = omc*ay*az - sn*ax;
    float r20 = omc*az*ax - sn*ay,    r21 = omc*az*ay + sn*ax,  r22 = cs + omc*az*az;
    float qr0 = r00*q0 + r01*q1 + r02*q2;
    float qr1 = r10*q0 + r11*q1 + r12*q2;
    float qr2 = r20*q0 + r21*q1 + r22*q2;
    float kr0 = r00*k0 + r01*k1 + r02*k2;
    float kr1 = r10*k0 + r11*k1 + r12*k2;
    float kr2 = r20*k0 + r21*k1 + r22*k2;
    float sc = fw[f] * gw * 0.57735026918962576f;
    int base = (h*512 + i)*192 + (g*4 + f)*3;
    Qw[base+0] = qr0*sc; Qw[base+1] = qr1*sc; Qw[base+2] = qr2*sc;
    Kst[base+0] = kr0;   Kst[base+1] = kr1;   Kst[base+2] = kr2;
  }
  for (int c = t; c < 384; c += 128){
    int hh = c / 48, cc = c % 48;
    V[(size_t)i*384 + c] = pr[384 + hh*96 + 48 + cc];
  }
  for (int qx = t; qx < 288; qx += 128){
    int ch = qx / 3, c3 = qx % 3;
    int hh = ch / 12, p = ch % 12;
    VP[(size_t)i*288 + qx] = pr[1152 + c3*160 + hh*20 + 8 + p];
  }
}

// ============ K3: z -> biasS (sqrt(1/3) folded, layout [h][i][j]) ============
__global__ __launch_bounds__(256) void zbias_kernel(
    const float* __restrict__ z, const float* __restrict__ wb, const float* __restrict__ bb,
    float* __restrict__ biasS)
{
  __shared__ float zs[8*1032];
  __shared__ float Wl[8*132];
  int i = blockIdx.y;
  int jt = blockIdx.x;
  int t = threadIdx.x;
  for (int r = 0; r < 4; r++){
    int e = t + 256*r;
    int ch = e & 7, k = e >> 3;
    Wl[ch*132 + k] = wb[k*8 + ch];
  }
  int cg = t >> 6, jg = t & 63;
  int ch0 = cg*2;
  float acc[2][4];
  #pragma unroll
  for (int c = 0; c < 2; c++)
    #pragma unroll
    for (int q = 0; q < 4; q++) acc[c][q] = 0.f;
  const float* zrow = z + ((size_t)i*512 + jt*256)*128;
  for (int kt = 0; kt < 4; kt++){
    __syncthreads();
    #pragma unroll
    for (int r = 0; r < 8; r++){
      int j = (t & 63) + 64*(r & 3);
      int kq = (t >> 6) + 4*(r >> 2);
      float4 v = *(const float4*)(zrow + (size_t)j*128 + kt*32 + kq*4);
      *(float4*)&zs[kq*1032 + j*4] = v;
    }
    __syncthreads();
    const float* wl0 = Wl + ch0*132 + kt*32;
    const float* wl1 = wl0 + 132;
    #pragma unroll
    for (int kq = 0; kq < 8; kq++){
      float4 w0 = *(const float4*)(wl0 + kq*4);
      float4 w1 = *(const float4*)(wl1 + kq*4);
      #pragma unroll
      for (int q = 0; q < 4; q++){
        float4 zv = *(const float4*)&zs[kq*1032 + (q*64 + jg)*4];
        acc[0][q] = fmaf(zv.x, w0.x, acc[0][q]);
        acc[0][q] = fmaf(zv.y, w0.y, acc[0][q]);
        acc[0][q] = fmaf(zv.z, w0.z, acc[0][q]);
        acc[0][q] = fmaf(zv.w, w0.w, acc[0][q]);
        acc[1][q] = fmaf(zv.x, w1.x, acc[1][q]);
        acc[1][q] = fmaf(zv.y, w1.y, acc[1][q]);
        acc[1][q] = fmaf(zv.z, w1.z, acc[1][q]);
        acc[1][q] = fmaf(zv.w, w1.w, acc[1][q]);
      }
    }
  }
  float b0 = bb[ch0], b1 = bb[ch0+1];
  #pragma unroll
  for (int q = 0; q < 4; q++){
    int j = jt*256 + q*64 + jg;
    biasS[(size_t)ch0*262144 + i*512 + j]     = 0.57735026918962576f * (acc[0][q] + b0);
    biasS[(size_t)(ch0+1)*262144 + i*512 + j] = 0.57735026918962576f * (acc[1][q] + b1);
  }
}

// ============ K4: scores + softmax, in-place over biasS -> a ============
// i-tile 8, grid (64, 8) -> 2 blocks/CU. Bias+mask prefetched into acc init.
__global__ __launch_bounds__(256) void scores_kernel(
    const float* __restrict__ Qw, const float* __restrict__ Kst,
    const float* __restrict__ mask, float* A)
{
  __shared__ float Ks[4*2056];    // plane k4: 512 j x 4 k
  __shared__ float Qs[4*40];      // plane k4: 8 i x 4 k
  int i0 = blockIdx.x * 8;
  int h = blockIdx.y;
  int t = threadIdx.x;
  int ig = t >> 6, jl = t & 63;
  const float* Kb = Kst + (size_t)h*512*192;
  const float* Qb = Qw + (size_t)(h*512 + i0)*192;
  float acc[2][8];
  // prefetch bias + mask into accumulator init (loads overlap whole K-loop)
  float mj[8];
  #pragma unroll
  for (int jt = 0; jt < 8; jt++) mj[jt] = mask[jt*64 + jl];
  #pragma unroll
  for (int q = 0; q < 2; q++){
    int i = i0 + ig*2 + q;
    float mi = mask[i];
    #pragma unroll
    for (int jt = 0; jt < 8; jt++){
      acc[q][jt] = A[((size_t)h*512 + i)*512 + jt*64 + jl] + 100000.0f*(mi*mj[jt] - 1.0f);
    }
  }
  for (int kc = 0; kc < 12; kc++){
    __syncthreads();
    {
      int k4 = t >> 6;
      #pragma unroll
      for (int r = 0; r < 8; r++){
        int j = (t & 63) + 64*r;
        float4 v = *(const float4*)(Kb + (size_t)j*192 + kc*16 + k4*4);
        *(float4*)&Ks[k4*2056 + j*4] = v;
      }
    }
    if (t < 32){
      int qi = t >> 2, k4 = t & 3;
      float4 v = *(const float4*)(Qb + (size_t)qi*192 + kc*16 + k4*4);
      *(float4*)&Qs[k4*40 + qi*4] = v;
    }
    __syncthreads();
    #pragma unroll
    for (int k4 = 0; k4 < 4; k4++){
      float4 qf[2];
      #pragma unroll
      for (int q = 0; q < 2; q++)
        qf[q] = *(const float4*)&Qs[k4*40 + (ig*2+q)*4];
      #pragma unroll
      for (int jt = 0; jt < 8; jt++){
        float4 kf = *(const float4*)&Ks[k4*2056 + (jt*64 + jl)*4];
        #pragma unroll
        for (int q = 0; q < 2; q++){
          acc[q][jt] = fmaf(qf[q].x, kf.x, acc[q][jt]);
          acc[q][jt] = fmaf(qf[q].y, kf.y, acc[q][jt]);
          acc[q][jt] = fmaf(qf[q].z, kf.z, acc[q][jt]);
          acc[q][jt] = fmaf(qf[q].w, kf.w, acc[q][jt]);
        }
      }
    }
  }
  #pragma unroll
  for (int q = 0; q < 2; q++){
    int i = i0 + ig*2 + q;
    float m = acc[q][0];
    #pragma unroll
    for (int jt = 1; jt < 8; jt++) m = fmaxf(m, acc[q][jt]);
    for (int off = 32; off > 0; off >>= 1) m = fmaxf(m, __shfl_xor(m, off));
    float ssum = 0.f;
    #pragma unroll
    for (int jt = 0; jt < 8; jt++){ acc[q][jt] = expf(acc[q][jt] - m); ssum += acc[q][jt]; }
    for (int off = 32; off > 0; off >>= 1) ssum += __shfl_xor(ssum, off);
    float invs = 1.0f / ssum;
    #pragma unroll
    for (int jt = 0; jt < 8; jt++){
      A[((size_t)h*512 + i)*512 + jt*64 + jl] = acc[q][jt] * invs;
    }
  }
}

// ============ K5: fused attention consumers: Y=a@z -> o_pair, o, o_pt, norms -> feats ============
// block = 2 i; single a_s staging serves all phases.
__global__ __launch_bounds__(256) void attnout_kernel(
    const float* __restrict__ A, const float* __restrict__ z,
    const float* __restrict__ wdz, const float* __restrict__ bdz,
    const float* __restrict__ V, const float* __restrict__ VP,
    float* __restrict__ feats)
{
  __shared__ float a_s[2*512*10];   // [il][j][h pad10] 40 KB
  __shared__ float Y_s[2*8*132];    // 8.25 KB
  __shared__ float opt_s[2][292];
  int i0 = blockIdx.x * 2;
  int t = threadIdx.x;
  // stage A for both i rows, all 8 h
  for (int r = 0; r < 32; r++){
    int e = t + 256*r;              // 8192 = 8h*2i*512j
    int hh = e >> 10, il = (e >> 9) & 1, j = e & 511;
    a_s[(il*512 + j)*10 + hh] = A[((size_t)hh*512 + i0 + il)*512 + j];
  }
  __syncthreads();
  // ---- Y phase: Y[il][h][k] = sum_j a[h,i,j] z[i,j,k] ----
  {
    int il = t >> 7, u = t & 127, hg = u >> 5, k4 = u & 31;
    const float* zb = z + ((size_t)(i0 + il)*512)*128 + k4*4;
    const float* asb = a_s + il*5120 + hg*2;
    float acc0[4], acc1[4];
    #pragma unroll
    for (int m = 0; m < 4; m++){ acc0[m] = 0.f; acc1[m] = 0.f; }
    #pragma unroll 8
    for (int j = 0; j < 512; j++){
      float2 a2 = *(const float2*)&asb[j*10];
      float4 zv = *(const float4*)(zb + (size_t)j*128);
      acc0[0] = fmaf(a2.x, zv.x, acc0[0]);
      acc0[1] = fmaf(a2.x, zv.y, acc0[1]);
      acc0[2] = fmaf(a2.x, zv.z, acc0[2]);
      acc0[3] = fmaf(a2.x, zv.w, acc0[3]);
      acc1[0] = fmaf(a2.y, zv.x, acc1[0]);
      acc1[1] = fmaf(a2.y, zv.y, acc1[1]);
      acc1[2] = fmaf(a2.y, zv.z, acc1[2]);
      acc1[3] = fmaf(a2.y, zv.w, acc1[3]);
    }
    *(float4*)&Y_s[((il*8) + hg*2 + 0)*132 + k4*4] = make_float4(acc0[0],acc0[1],acc0[2],acc0[3]);
    *(float4*)&Y_s[((il*8) + hg*2 + 1)*132 + k4*4] = make_float4(acc1[0],acc1[1],acc1[2],acc1[3]);
  }
  __syncthreads();
  // ---- o_pair phase: o_pair[il][h][c] = Y[il][h][:] @ wdz[:,c] + bdz ----
  {
    int il = t >> 7, u = t & 127, hh = u >> 4, cp = u & 15;
    const float* Yr = Y_s + (il*8 + hh)*132;
    float s0 = bdz[cp*2], s1 = bdz[cp*2+1];
    #pragma unroll 8
    for (int k = 0; k < 128; k++){
      float yv = Yr[k];
      float2 w2 = *(const float2*)(wdz + (size_t)k*32 + cp*2);
      s0 = fmaf(yv, w2.x, s0);
      s1 = fmaf(yv, w2.y, s1);
    }
    float* fp = feats + (size_t)(i0 + il)*1024 + 768 + hh*32 + cp*2;
    fp[0] = s0; fp[1] = s1;
  }
  // ---- o / o_pt phase (uses a_s, untouched) ----
  {
    bool act = (t < 168);
    const float* base = V; int stride = 384; int hh = 0;
    int ch = t*4;
    if (act){
      if (ch < 384){ hh = ch/48; base = V + ch; stride = 384; }
      else { int qq = ch - 384; hh = qq/36; base = VP + qq; stride = 288; }
    }
    float acc0[4], acc1[4];
    #pragma unroll
    for (int m = 0; m < 4; m++){ acc0[m] = 0.f; acc1[m] = 0.f; }
    if (act){
      const float* a0 = a_s + hh;
      const float* a1 = a_s + 5120 + hh;
      #pragma unroll 4
      for (int j = 0; j < 512; j++){
        float ax = a0[j*10];
        float ay = a1[j*10];
        float4 v4 = *(const float4*)(base + (size_t)j*stride);
        acc0[0] = fmaf(ax, v4.x, acc0[0]);
        acc0[1] = fmaf(ax, v4.y, acc0[1]);
        acc0[2] = fmaf(ax, v4.z, acc0[2]);
        acc0[3] = fmaf(ax, v4.w, acc0[3]);
        acc1[0] = fmaf(ay, v4.x, acc1[0]);
        acc1[1] = fmaf(ay, v4.y, acc1[1]);
        acc1[2] = fmaf(ay, v4.z, acc1[2]);
        acc1[3] = fmaf(ay, v4.w, acc1[3]);
      }
      if (ch < 384){
        *(float4*)&feats[(size_t)i0*1024 + ch]     = make_float4(acc0[0],acc0[1],acc0[2],acc0[3]);
        *(float4*)&feats[(size_t)(i0+1)*1024 + ch] = make_float4(acc1[0],acc1[1],acc1[2],acc1[3]);
      } else {
        int qq = ch - 384;
        #pragma unroll
        for (int m = 0; m < 4; m++){
          opt_s[0][qq + m] = acc0[m];
          opt_s[1][qq + m] = acc1[m];
        }
      }
    }
  }
  __syncthreads();
  if (t < 192){
    int il = t / 96, p = t % 96;
    float x = opt_s[il][p*3], y = opt_s[il][p*3+1], zz = opt_s[il][p*3+2];
    float* fr = feats + (size_t)(i0 + il)*1024;
    fr[384 + p] = x;
    fr[480 + p] = y;
    fr[576 + p] = zz;
    fr[672 + p] = sqrtf(x*x + y*y + zz*zz + 1e-8f);
  }
}

// ============ K6: out = feats @ wout (+bout in reduce); split-K=8 partials ============
__global__ __launch_bounds__(256) void outgemm_kernel(
    const float* __restrict__ feats, const float* __restrict__ wout,
    float* __restrict__ part)
{
  __shared__ float fA[32*68];
  __shared__ float fB[32*68];
  int ct = blockIdx.x;
  int it = blockIdx.y;
  int sk = blockIdx.z;
  int i0 = it*64, c0 = ct*64, k0 = sk*128;
  int t = threadIdx.x;
  int ir = t >> 4, cr = t & 15;
  float acc[4][4];
  #pragma unroll
  for (int q = 0; q < 4; q++)
    #pragma unroll
    for (int p = 0; p < 4; p++) acc[q][p] = 0.f;
  for (int kt = 0; kt < 128; kt += 32){
    __syncthreads();
    #pragma unroll
    for (int r = 0; r < 2; r++){
      int e = t + 256*r;
      int i = e & 63, kq = e >> 6;
      float4 v = *(const float4*)(feats + (size_t)(i0 + i)*1024 + k0 + kt + kq*4);
      fA[(kq*4+0)*68 + i] = v.x; fA[(kq*4+1)*68 + i] = v.y;
      fA[(kq*4+2)*68 + i] = v.z; fA[(kq*4+3)*68 + i] = v.w;
    }
    #pragma unroll
    for (int r = 0; r < 2; r++){
      int e = t + 256*r;
      int kk = e >> 4, c4 = e & 15;
      float4 v = *(const float4*)(wout + (size_t)(k0 + kt + kk)*384 + c0 + c4*4);
      *(float4*)&fB[kk*68 + c4*4] = v;
    }
    __syncthreads();
    #pragma unroll 8
    for (int k = 0; k < 32; k++){
      float4 a4 = *(const float4*)&fA[k*68 + ir*4];
      float4 b4 = *(const float4*)&fB[k*68 + cr*4];
      acc[0][0] = fmaf(a4.x, b4.x, acc[0][0]);
      acc[0][1] = fmaf(a4.x, b4.y, acc[0][1]);
      acc[0][2] = fmaf(a4.x, b4.z, acc[0][2]);
      acc[0][3] = fmaf(a4.x, b4.w, acc[0][3]);
      acc[1][0] = fmaf(a4.y, b4.x, acc[1][0]);
      acc[1][1] = fmaf(a4.y, b4.y, acc[1][1]);
      acc[1][2] = fmaf(a4.y, b4.z, acc[1][2]);
      acc[1][3] = fmaf(a4.y, b4.w, acc[1][3]);
      acc[2][0] = fmaf(a4.z, b4.x, acc[2][0]);
      acc[2][1] = fmaf(a4.z, b4.y, acc[2][1]);
      acc[2][2] = fmaf(a4.z, b4.z, acc[2][2]);
      acc[2][3] = fmaf(a4.z, b4.w, acc[2][3]);
      acc[3][0] = fmaf(a4.w, b4.x, acc[3][0]);
      acc[3][1] = fmaf(a4.w, b4.y, acc[3][1]);
      acc[3][2] = fmaf(a4.w, b4.z, acc[3][2]);
      acc[3][3] = fmaf(a4.w, b4.w, acc[3][3]);
    }
  }
  float* pb = part + ((size_t)sk*512 + i0)*384 + c0;
  #pragma unroll
  for (int q = 0; q < 4; q++){
    float4 o;
    o.x = acc[q][0]; o.y = acc[q][1]; o.z = acc[q][2]; o.w = acc[q][3];
    *(float4*)&pb[(size_t)(ir*4 + q)*384 + cr*4] = o;
  }
}

__global__ __launch_bounds__(256) void outreduce_kernel(
    const float* __restrict__ part, const float* __restrict__ bout,
    float* __restrict__ out)
{
  int e = blockIdx.x*256 + threadIdx.x;
  float4 acc = *(const float4*)(bout + (e % 96)*4);
  #pragma unroll
  for (int sk = 0; sk < 8; sk++){
    float4 p = *(const float4*)(part + (size_t)sk*196608 + (size_t)e*4);
    acc.x += p.x; acc.y += p.y; acc.z += p.z; acc.w += p.w;
  }
  *(float4*)(out + (size_t)e*4) = acc;
}

extern "C" void kernel_launch(void* const* d_in, const int* in_sizes, int n_in,
                              void* d_out, int out_size, void* d_ws, size_t ws_size,
                              hipStream_t stream)
{
  const float* s    = (const float*)d_in[0];
  const float* z    = (const float*)d_in[1];
  const float* rotv = (const float*)d_in[2];
  const float* mask = (const float*)d_in[3];
  const float* wq   = (const float*)d_in[4];
  const float* bq   = (const float*)d_in[5];
  const float* wkv  = (const float*)d_in[6];
  const float* bkv  = (const float*)d_in[7];
  const float* wkvp = (const float*)d_in[8];
  const float* bkvp = (const float*)d_in[9];
  const float* wb   = (const float*)d_in[10];
  const float* bb   = (const float*)d_in[11];
  const float* wdz  = (const float*)d_in[12];
  const float* bdz  = (const float*)d_in[13];
  const float* wout = (const float*)d_in[14];
  const float* bout = (const float*)d_in[15];
  const float* lfa  = (const float*)d_in[16];
  const float* gwts = (const float*)d_in[17];
  const float* fwts = (const float*)d_in[18];
  float* out = (float*)d_out;
  float* ws  = (float*)d_ws;

  float* proj  = ws + OFF_PROJ;
  float* Qw    = ws + OFF_QW;
  float* Kst   = ws + OFF_KST;
  float* V     = ws + OFF_V;
  float* VP    = ws + OFF_VP;
  float* A     = ws + OFF_A;     // biasS, overwritten in-place by softmax probs
  float* feats = ws + OFF_FEATS;
  float* part  = ws + OFF_PART;

  proj_kernel     <<<dim3(26, 16), 256, 0, stream>>>(s, wq, bq, wkv, bkv, wkvp, bkvp, proj);
  node_kernel     <<<dim3(512),    128, 0, stream>>>(proj, rotv, lfa, gwts, fwts, Qw, Kst, V, VP);
  zbias_kernel    <<<dim3(2, 512), 256, 0, stream>>>(z, wb, bb, A);
  scores_kernel   <<<dim3(64, 8),  256, 0, stream>>>(Qw, Kst, mask, A);
  attnout_kernel  <<<dim3(256),    256, 0, stream>>>(A, z, wdz, bdz, V, VP, feats);
  outgemm_kernel  <<<dim3(6, 8, 8),256, 0, stream>>>(feats, wout, part);
  outreduce_kernel<<<dim3(192),    256, 0, stream>>>(part, bout, out);
}

// Round 4
// 391.456 us; speedup vs baseline: 1.0822x; 1.0822x over previous
//
#include <hip/hip_runtime.h>
#include <math.h>

// Problem constants (B=1)
// N=512, CS=384, CZ=128, G=16, CH=48, H=8, PQ=8, PV=12, NF=4, CZ4=32
// feats dim = 384 (o) + 96*3 (o_pt xyz) + 96 (norm) + 256 (o_pair) = 1024

// ---- workspace layout (floats) ----
#define OFF_PROJ 0
#define SZ_PROJ (512*1632)
#define OFF_QW (OFF_PROJ + SZ_PROJ)
#define SZ_QW (8*512*192)
#define OFF_KST (OFF_QW + SZ_QW)
#define OFF_VCAT (OFF_KST + SZ_QW)
#define SZ_VCAT (512*768)
#define OFF_A (OFF_VCAT + SZ_VCAT)
#define SZ_A (8*512*512)
#define OFF_FEATS (OFF_A + SZ_A)
#define SZ_FEATS (512*1024)
#define OFF_PART (OFF_FEATS + SZ_FEATS)
#define SZ_PART (8*512*384)

// ============ K1: s @ [wq|wkv|wkvp] + bias -> proj (512 x 1632) ============
__global__ __launch_bounds__(256) void proj_kernel(
    const float* __restrict__ s, const float* __restrict__ wq, const float* __restrict__ bq,
    const float* __restrict__ wkv, const float* __restrict__ bkv,
    const float* __restrict__ wkvp, const float* __restrict__ bkvp,
    float* __restrict__ proj)
{
  __shared__ float sT[384][34];
  int ct = blockIdx.x;          // 26 col tiles of 64
  int i0 = blockIdx.y * 32;
  int col0 = ct * 64;
  const float* W; const float* bias; int wld, wcol0;
  if (col0 < 384)       { W = wq;   bias = bq;   wld = 384; wcol0 = col0; }
  else if (col0 < 1152) { W = wkv;  bias = bkv;  wld = 768; wcol0 = col0 - 384; }
  else                  { W = wkvp; bias = bkvp; wld = 480; wcol0 = col0 - 1152; }
  int t = threadIdx.x;
  #pragma unroll
  for (int r = 0; r < 12; r++){
    int e = t + 256*r;
    int i = e & 31;
    int k4 = e >> 5;            // 0..95
    float4 v = *(const float4*)(s + (size_t)(i0 + i)*384 + k4*4);
    sT[k4*4+0][i] = v.x; sT[k4*4+1][i] = v.y; sT[k4*4+2][i] = v.z; sT[k4*4+3][i] = v.w;
  }
  __syncthreads();
  int cr = t & 15;
  int ipair = t >> 4;
  int ii = ipair * 2;
  int wc = wcol0 + cr*4;
  bool valid = (wc + 4 <= wld);
  int wcc = valid ? wc : (wld - 4);
  float acc[2][4];
  #pragma unroll
  for (int q = 0; q < 2; q++)
    #pragma unroll
    for (int p = 0; p < 4; p++) acc[q][p] = 0.f;
  #pragma unroll 4
  for (int k = 0; k < 384; k++){
    float2 a2 = *(const float2*)&sT[k][ii];
    float4 w4 = *(const float4*)(W + (size_t)k*wld + wcc);
    acc[0][0] = fmaf(a2.x, w4.x, acc[0][0]);
    acc[0][1] = fmaf(a2.x, w4.y, acc[0][1]);
    acc[0][2] = fmaf(a2.x, w4.z, acc[0][2]);
    acc[0][3] = fmaf(a2.x, w4.w, acc[0][3]);
    acc[1][0] = fmaf(a2.y, w4.x, acc[1][0]);
    acc[1][1] = fmaf(a2.y, w4.y, acc[1][1]);
    acc[1][2] = fmaf(a2.y, w4.z, acc[1][2]);
    acc[1][3] = fmaf(a2.y, w4.w, acc[1][3]);
  }
  if (valid){
    float4 bv = *(const float4*)(bias + wc);
    #pragma unroll
    for (int q = 0; q < 2; q++){
      int row = i0 + ii + q;
      float4 o;
      o.x = acc[q][0] + bv.x; o.y = acc[q][1] + bv.y;
      o.z = acc[q][2] + bv.z; o.w = acc[q][3] + bv.w;
      *(float4*)(proj + (size_t)row*1632 + col0 + cr*4) = o;
    }
  }
}

// ============ K2: per-node rotation + pack Qw/Kst (192-d), Vcat [j][h][96] ============
__global__ __launch_bounds__(128) void node_kernel(
    const float* __restrict__ proj, const float* __restrict__ rotvec,
    const float* __restrict__ lfa, const float* __restrict__ gwts, const float* __restrict__ fwts,
    float* __restrict__ Qw, float* __restrict__ Kst, float* __restrict__ Vcat)
{
  int i = blockIdx.x, t = threadIdx.x;
  const float* pr = proj + (size_t)i*1632;
  float rx = rotvec[i*3], ry = rotvec[i*3+1], rz = rotvec[i*3+2];
  float nrm = sqrtf(rx*rx + ry*ry + rz*rz);
  float angle = nrm + 1e-8f;
  float inv = 1.0f / fmaxf(nrm, 1e-12f);
  float ax = rx*inv, ay = ry*inv, az = rz*inv;
  float f0 = fwts[0], f1 = fwts[1], f2 = fwts[2], f3 = fwts[3];
  float mfw = fmaxf(fmaxf(f0,f1), fmaxf(f2,f3));
  float e0 = expf(f0-mfw), e1 = expf(f1-mfw), e2 = expf(f2-mfw), e3 = expf(f3-mfw);
  float esum = e0+e1+e2+e3;
  float fw[4] = {e0/esum, e1/esum, e2/esum, e3/esum};
  float fq[4] = { 1.0f*expf(lfa[0]), 0.35355339059327373f*expf(lfa[1]),
                  0.125f*expf(lfa[2]), 0.04419417382415922f*expf(lfa[3]) };
  int h = t >> 4, g = t & 15;
  float gw = log1pf(expf(gwts[g])) * 0.25f;
  float q0 = pr[h*48 + g*3 + 0], q1 = pr[h*48 + g*3 + 1], q2 = pr[h*48 + g*3 + 2];
  float k0 = pr[384 + h*96 + g*3 + 0], k1 = pr[384 + h*96 + g*3 + 1], k2 = pr[384 + h*96 + g*3 + 2];
  #pragma unroll
  for (int f = 0; f < 4; f++){
    float th = angle * fq[f];
    float sn = sinf(th), cs = cosf(th), omc = 1.0f - cs;
    float r00 = cs + omc*ax*ax,       r01 = omc*ax*ay - sn*az,  r02 = omc*ax*az + sn*ay;
    float r10 = omc*ay*ax + sn*az,    r11 = cs + omc*ay*ay,     r12 = omc*ay*az - sn*ax;
    float r20 = omc*az*ax - sn*ay,    r21 = omc*az*ay + sn*ax,  r22 = cs + omc*az*az;
    float qr0 = r00*q0 + r01*q1 + r02*q2;
    float qr1 = r10*q0 + r11*q1 + r12*q2;
    float qr2 = r20*q0 + r21*q1 + r22*q2;
    float kr0 = r00*k0 + r01*k1 + r02*k2;
    float kr1 = r10*k0 + r11*k1 + r12*k2;
    float kr2 = r20*k0 + r21*k1 + r22*k2;
    float sc = fw[f] * gw * 0.57735026918962576f;
    int base = (h*512 + i)*192 + (g*4 + f)*3;
    Qw[base+0] = qr0*sc; Qw[base+1] = qr1*sc; Qw[base+2] = qr2*sc;
    Kst[base+0] = kr0;   Kst[base+1] = kr1;   Kst[base+2] = kr2;
  }
  // Vcat[j][h][96]: c<48 = V; c = 48 + p*3 + axis = o_pt source
  for (int c = t; c < 384; c += 128){
    int hh = c / 48, cc = c % 48;
    Vcat[(size_t)i*768 + hh*96 + cc] = pr[384 + hh*96 + 48 + cc];
  }
  for (int e = t; e < 288; e += 128){
    int hh = e / 36, r = e % 36;
    int p = r / 3, axv = r % 3;
    Vcat[(size_t)i*768 + hh*96 + 48 + p*3 + axv] = pr[1152 + axv*160 + hh*20 + 8 + p];
  }
}

// ============ K3: z -> biasS (sqrt(1/3) folded, layout [h][i][j]) ============
__global__ __launch_bounds__(256) void zbias_kernel(
    const float* __restrict__ z, const float* __restrict__ wb, const float* __restrict__ bb,
    float* __restrict__ biasS)
{
  __shared__ float zs[8*1032];
  __shared__ float Wl[8*132];
  int i = blockIdx.y;
  int jt = blockIdx.x;
  int t = threadIdx.x;
  for (int r = 0; r < 4; r++){
    int e = t + 256*r;
    int ch = e & 7, k = e >> 3;
    Wl[ch*132 + k] = wb[k*8 + ch];
  }
  int cg = t >> 6, jg = t & 63;
  int ch0 = cg*2;
  float acc[2][4];
  #pragma unroll
  for (int c = 0; c < 2; c++)
    #pragma unroll
    for (int q = 0; q < 4; q++) acc[c][q] = 0.f;
  const float* zrow = z + ((size_t)i*512 + jt*256)*128;
  for (int kt = 0; kt < 4; kt++){
    __syncthreads();
    #pragma unroll
    for (int r = 0; r < 8; r++){
      int j = (t & 63) + 64*(r & 3);
      int kq = (t >> 6) + 4*(r >> 2);
      float4 v = *(const float4*)(zrow + (size_t)j*128 + kt*32 + kq*4);
      *(float4*)&zs[kq*1032 + j*4] = v;
    }
    __syncthreads();
    const float* wl0 = Wl + ch0*132 + kt*32;
    const float* wl1 = wl0 + 132;
    #pragma unroll
    for (int kq = 0; kq < 8; kq++){
      float4 w0 = *(const float4*)(wl0 + kq*4);
      float4 w1 = *(const float4*)(wl1 + kq*4);
      #pragma unroll
      for (int q = 0; q < 4; q++){
        float4 zv = *(const float4*)&zs[kq*1032 + (q*64 + jg)*4];
        acc[0][q] = fmaf(zv.x, w0.x, acc[0][q]);
        acc[0][q] = fmaf(zv.y, w0.y, acc[0][q]);
        acc[0][q] = fmaf(zv.z, w0.z, acc[0][q]);
        acc[0][q] = fmaf(zv.w, w0.w, acc[0][q]);
        acc[1][q] = fmaf(zv.x, w1.x, acc[1][q]);
        acc[1][q] = fmaf(zv.y, w1.y, acc[1][q]);
        acc[1][q] = fmaf(zv.z, w1.z, acc[1][q]);
        acc[1][q] = fmaf(zv.w, w1.w, acc[1][q]);
      }
    }
  }
  float b0 = bb[ch0], b1 = bb[ch0+1];
  #pragma unroll
  for (int q = 0; q < 4; q++){
    int j = jt*256 + q*64 + jg;
    biasS[(size_t)ch0*262144 + i*512 + j]     = 0.57735026918962576f * (acc[0][q] + b0);
    biasS[(size_t)(ch0+1)*262144 + i*512 + j] = 0.57735026918962576f * (acc[1][q] + b1);
  }
}

// ============ K4: scores + softmax, in-place over biasS -> a ============
__global__ __launch_bounds__(256) void scores_kernel(
    const float* __restrict__ Qw, const float* __restrict__ Kst,
    const float* __restrict__ mask, float* A)
{
  __shared__ float Ks[4*2056];    // plane k4: 512 j x 4 k
  __shared__ float Qs[4*40];      // plane k4: 8 i x 4 k
  int i0 = blockIdx.x * 8;
  int h = blockIdx.y;
  int t = threadIdx.x;
  int ig = t >> 6, jl = t & 63;
  const float* Kb = Kst + (size_t)h*512*192;
  const float* Qb = Qw + (size_t)(h*512 + i0)*192;
  float acc[2][8];
  float mj[8];
  #pragma unroll
  for (int jt = 0; jt < 8; jt++) mj[jt] = mask[jt*64 + jl];
  #pragma unroll
  for (int q = 0; q < 2; q++){
    int i = i0 + ig*2 + q;
    float mi = mask[i];
    #pragma unroll
    for (int jt = 0; jt < 8; jt++){
      acc[q][jt] = A[((size_t)h*512 + i)*512 + jt*64 + jl] + 100000.0f*(mi*mj[jt] - 1.0f);
    }
  }
  for (int kc = 0; kc < 12; kc++){
    __syncthreads();
    {
      int k4 = t >> 6;
      #pragma unroll
      for (int r = 0; r < 8; r++){
        int j = (t & 63) + 64*r;
        float4 v = *(const float4*)(Kb + (size_t)j*192 + kc*16 + k4*4);
        *(float4*)&Ks[k4*2056 + j*4] = v;
      }
    }
    if (t < 32){
      int qi = t >> 2, k4 = t & 3;
      float4 v = *(const float4*)(Qb + (size_t)qi*192 + kc*16 + k4*4);
      *(float4*)&Qs[k4*40 + qi*4] = v;
    }
    __syncthreads();
    #pragma unroll
    for (int k4 = 0; k4 < 4; k4++){
      float4 qf[2];
      #pragma unroll
      for (int q = 0; q < 2; q++)
        qf[q] = *(const float4*)&Qs[k4*40 + (ig*2+q)*4];
      #pragma unroll
      for (int jt = 0; jt < 8; jt++){
        float4 kf = *(const float4*)&Ks[k4*2056 + (jt*64 + jl)*4];
        #pragma unroll
        for (int q = 0; q < 2; q++){
          acc[q][jt] = fmaf(qf[q].x, kf.x, acc[q][jt]);
          acc[q][jt] = fmaf(qf[q].y, kf.y, acc[q][jt]);
          acc[q][jt] = fmaf(qf[q].z, kf.z, acc[q][jt]);
          acc[q][jt] = fmaf(qf[q].w, kf.w, acc[q][jt]);
        }
      }
    }
  }
  #pragma unroll
  for (int q = 0; q < 2; q++){
    int i = i0 + ig*2 + q;
    float m = acc[q][0];
    #pragma unroll
    for (int jt = 1; jt < 8; jt++) m = fmaxf(m, acc[q][jt]);
    for (int off = 32; off > 0; off >>= 1) m = fmaxf(m, __shfl_xor(m, off));
    float ssum = 0.f;
    #pragma unroll
    for (int jt = 0; jt < 8; jt++){ acc[q][jt] = expf(acc[q][jt] - m); ssum += acc[q][jt]; }
    for (int off = 32; off > 0; off >>= 1) ssum += __shfl_xor(ssum, off);
    float invs = 1.0f / ssum;
    #pragma unroll
    for (int jt = 0; jt < 8; jt++){
      A[((size_t)h*512 + i)*512 + jt*64 + jl] = acc[q][jt] * invs;
    }
  }
}

// ============ K5a: Y = a@z (1 i per block), o_pair = Y@wdz + bdz -> feats[768..1024) ============
// grid 512 -> 2 blocks/CU. j-loop split across wave halves, LDS reduce.
__global__ __launch_bounds__(256) void yopair_kernel(
    const float* __restrict__ A, const float* __restrict__ z,
    const float* __restrict__ wdz, const float* __restrict__ bdz,
    float* __restrict__ feats)
{
  __shared__ float a_s[512*10];     // [j][h] pad 10, 20.5 KB
  __shared__ float Y_s[8*132];      // 4.2 KB
  int i = blockIdx.x;
  int t = threadIdx.x;
  #pragma unroll
  for (int r = 0; r < 4; r++){
    int idx = t + r*256;            // 1024 = 8h * 128 j4
    int h = idx >> 7, j4 = idx & 127;
    float4 v = *(const float4*)(A + ((size_t)h*512 + i)*512 + j4*4);
    a_s[(j4*4+0)*10 + h] = v.x;
    a_s[(j4*4+1)*10 + h] = v.y;
    a_s[(j4*4+2)*10 + h] = v.z;
    a_s[(j4*4+3)*10 + h] = v.w;
  }
  __syncthreads();
  int jh = t >> 7;                  // j-half
  int u = t & 127, hg = u >> 5, k4 = u & 31;
  int h0 = hg*2;
  const float* zb = z + ((size_t)i*512 + jh*256)*128 + k4*4;
  const float* ap = a_s + (jh*256)*10 + h0;
  float acc0[4], acc1[4];
  #pragma unroll
  for (int m = 0; m < 4; m++){ acc0[m] = 0.f; acc1[m] = 0.f; }
  #pragma unroll 8
  for (int j = 0; j < 256; j++){
    float2 a2 = *(const float2*)&ap[j*10];
    float4 zv = *(const float4*)(zb + (size_t)j*128);
    acc0[0] = fmaf(a2.x, zv.x, acc0[0]);
    acc0[1] = fmaf(a2.x, zv.y, acc0[1]);
    acc0[2] = fmaf(a2.x, zv.z, acc0[2]);
    acc0[3] = fmaf(a2.x, zv.w, acc0[3]);
    acc1[0] = fmaf(a2.y, zv.x, acc1[0]);
    acc1[1] = fmaf(a2.y, zv.y, acc1[1]);
    acc1[2] = fmaf(a2.y, zv.z, acc1[2]);
    acc1[3] = fmaf(a2.y, zv.w, acc1[3]);
  }
  if (jh == 0){
    *(float4*)&Y_s[h0*132 + k4*4]     = make_float4(acc0[0],acc0[1],acc0[2],acc0[3]);
    *(float4*)&Y_s[(h0+1)*132 + k4*4] = make_float4(acc1[0],acc1[1],acc1[2],acc1[3]);
  }
  __syncthreads();
  if (jh == 1){
    float4 p0 = *(const float4*)&Y_s[h0*132 + k4*4];
    float4 p1 = *(const float4*)&Y_s[(h0+1)*132 + k4*4];
    p0.x += acc0[0]; p0.y += acc0[1]; p0.z += acc0[2]; p0.w += acc0[3];
    p1.x += acc1[0]; p1.y += acc1[1]; p1.z += acc1[2]; p1.w += acc1[3];
    *(float4*)&Y_s[h0*132 + k4*4]     = p0;
    *(float4*)&Y_s[(h0+1)*132 + k4*4] = p1;
  }
  __syncthreads();
  // o_pair: thread (h, c)
  int h = t >> 5, c = t & 31;
  float sacc = bdz[c];
  const float* Yr = Y_s + h*132;
  #pragma unroll 8
  for (int k = 0; k < 128; k++){
    sacc = fmaf(Yr[k], wdz[(size_t)k*32 + c], sacc);
  }
  feats[(size_t)i*1024 + 768 + h*32 + c] = sacc;
}

// ============ K5b: per-h GEMM: o + o_pt + norms -> feats[0..768) ============
// grid (32 i-tiles of 16, 8 h); Vcat staged in LDS, reused across 16 i.
__global__ __launch_bounds__(256) void ovgemm_kernel(
    const float* __restrict__ A, const float* __restrict__ Vcat,
    float* __restrict__ feats)
{
  __shared__ float A_s[64*18];      // [k][i], 4.6 KB
  __shared__ float V_s[64*100];     // [k][c], 25.6 KB
  __shared__ float opt[16*40];      // o_pt staging for norms
  int i0 = blockIdx.x * 16;
  int h = blockIdx.y;
  int t = threadIdx.x;
  int ip = t >> 5;                  // i-pair index 0..7
  int cg = t & 31;                  // c-quad 0..31 (active < 24)
  float acc[2][4];
  #pragma unroll
  for (int q = 0; q < 2; q++)
    #pragma unroll
    for (int m = 0; m < 4; m++) acc[q][m] = 0.f;
  for (int cb = 0; cb < 512; cb += 64){
    __syncthreads();
    {
      int ii = t >> 4, j4 = t & 15;
      float4 v = *(const float4*)(A + ((size_t)h*512 + i0 + ii)*512 + cb + j4*4);
      A_s[(j4*4+0)*18 + ii] = v.x;
      A_s[(j4*4+1)*18 + ii] = v.y;
      A_s[(j4*4+2)*18 + ii] = v.z;
      A_s[(j4*4+3)*18 + ii] = v.w;
    }
    #pragma unroll
    for (int r = 0; r < 6; r++){
      int idx = t + r*256;          // 1536 = 64 j * 24 cq
      int j = idx / 24, cq = idx % 24;
      float4 v = *(const float4*)(Vcat + (size_t)(cb + j)*768 + h*96 + cq*4);
      *(float4*)&V_s[j*100 + cq*4] = v;
    }
    __syncthreads();
    #pragma unroll 4
    for (int k = 0; k < 64; k++){
      float2 a2 = *(const float2*)&A_s[k*18 + ip*2];
      float4 v4 = *(const float4*)&V_s[k*100 + cg*4];
      acc[0][0] = fmaf(a2.x, v4.x, acc[0][0]);
      acc[0][1] = fmaf(a2.x, v4.y, acc[0][1]);
      acc[0][2] = fmaf(a2.x, v4.z, acc[0][2]);
      acc[0][3] = fmaf(a2.x, v4.w, acc[0][3]);
      acc[1][0] = fmaf(a2.y, v4.x, acc[1][0]);
      acc[1][1] = fmaf(a2.y, v4.y, acc[1][1]);
      acc[1][2] = fmaf(a2.y, v4.z, acc[1][2]);
      acc[1][3] = fmaf(a2.y, v4.w, acc[1][3]);
    }
  }
  int c0 = cg*4;
  if (c0 < 48){
    #pragma unroll
    for (int q = 0; q < 2; q++){
      *(float4*)&feats[(size_t)(i0 + ip*2 + q)*1024 + h*48 + c0] =
        make_float4(acc[q][0], acc[q][1], acc[q][2], acc[q][3]);
    }
  } else if (c0 < 84){
    #pragma unroll
    for (int q = 0; q < 2; q++){
      #pragma unroll
      for (int m = 0; m < 4; m++){
        opt[(ip*2+q)*40 + (c0 - 48 + m)] = acc[q][m];
      }
    }
  }
  __syncthreads();
  if (t < 192){
    int il = t / 12, p = t % 12;
    float x = opt[il*40 + p*3], y = opt[il*40 + p*3 + 1], zz = opt[il*40 + p*3 + 2];
    float* fr = feats + (size_t)(i0 + il)*1024;
    fr[384 + h*12 + p] = x;
    fr[480 + h*12 + p] = y;
    fr[576 + h*12 + p] = zz;
    fr[672 + h*12 + p] = sqrtf(x*x + y*y + zz*zz + 1e-8f);
  }
}

// ============ K6: out = feats @ wout (+bout in reduce); split-K=8 partials ============
__global__ __launch_bounds__(256) void outgemm_kernel(
    const float* __restrict__ feats, const float* __restrict__ wout,
    float* __restrict__ part)
{
  __shared__ float fA[32*68];
  __shared__ float fB[32*68];
  int ct = blockIdx.x;
  int it = blockIdx.y;
  int sk = blockIdx.z;
  int i0 = it*64, c0 = ct*64, k0 = sk*128;
  int t = threadIdx.x;
  int ir = t >> 4, cr = t & 15;
  float acc[4][4];
  #pragma unroll
  for (int q = 0; q < 4; q++)
    #pragma unroll
    for (int p = 0; p < 4; p++) acc[q][p] = 0.f;
  for (int kt = 0; kt < 128; kt += 32){
    __syncthreads();
    #pragma unroll
    for (int r = 0; r < 2; r++){
      int e = t + 256*r;
      int i = e & 63, kq = e >> 6;
      float4 v = *(const float4*)(feats + (size_t)(i0 + i)*1024 + k0 + kt + kq*4);
      fA[(kq*4+0)*68 + i] = v.x; fA[(kq*4+1)*68 + i] = v.y;
      fA[(kq*4+2)*68 + i] = v.z; fA[(kq*4+3)*68 + i] = v.w;
    }
    #pragma unroll
    for (int r = 0; r < 2; r++){
      int e = t + 256*r;
      int kk = e >> 4, c4 = e & 15;
      float4 v = *(const float4*)(wout + (size_t)(k0 + kt + kk)*384 + c0 + c4*4);
      *(float4*)&fB[kk*68 + c4*4] = v;
    }
    __syncthreads();
    #pragma unroll 8
    for (int k = 0; k < 32; k++){
      float4 a4 = *(const float4*)&fA[k*68 + ir*4];
      float4 b4 = *(const float4*)&fB[k*68 + cr*4];
      acc[0][0] = fmaf(a4.x, b4.x, acc[0][0]);
      acc[0][1] = fmaf(a4.x, b4.y, acc[0][1]);
      acc[0][2] = fmaf(a4.x, b4.z, acc[0][2]);
      acc[0][3] = fmaf(a4.x, b4.w, acc[0][3]);
      acc[1][0] = fmaf(a4.y, b4.x, acc[1][0]);
      acc[1][1] = fmaf(a4.y, b4.y, acc[1][1]);
      acc[1][2] = fmaf(a4.y, b4.z, acc[1][2]);
      acc[1][3] = fmaf(a4.y, b4.w, acc[1][3]);
      acc[2][0] = fmaf(a4.z, b4.x, acc[2][0]);
      acc[2][1] = fmaf(a4.z, b4.y, acc[2][1]);
      acc[2][2] = fmaf(a4.z, b4.z, acc[2][2]);
      acc[2][3] = fmaf(a4.z, b4.w, acc[2][3]);
      acc[3][0] = fmaf(a4.w, b4.x, acc[3][0]);
      acc[3][1] = fmaf(a4.w, b4.y, acc[3][1]);
      acc[3][2] = fmaf(a4.w, b4.z, acc[3][2]);
      acc[3][3] = fmaf(a4.w, b4.w, acc[3][3]);
    }
  }
  float* pb = part + ((size_t)sk*512 + i0)*384 + c0;
  #pragma unroll
  for (int q = 0; q < 4; q++){
    float4 o;
    o.x = acc[q][0]; o.y = acc[q][1]; o.z = acc[q][2]; o.w = acc[q][3];
    *(float4*)&pb[(size_t)(ir*4 + q)*384 + cr*4] = o;
  }
}

__global__ __launch_bounds__(256) void outreduce_kernel(
    const float* __restrict__ part, const float* __restrict__ bout,
    float* __restrict__ out)
{
  int e = blockIdx.x*256 + threadIdx.x;
  float4 acc = *(const float4*)(bout + (e % 96)*4);
  #pragma unroll
  for (int sk = 0; sk < 8; sk++){
    float4 p = *(const float4*)(part + (size_t)sk*196608 + (size_t)e*4);
    acc.x += p.x; acc.y += p.y; acc.z += p.z; acc.w += p.w;
  }
  *(float4*)(out + (size_t)e*4) = acc;
}

extern "C" void kernel_launch(void* const* d_in, const int* in_sizes, int n_in,
                              void* d_out, int out_size, void* d_ws, size_t ws_size,
                              hipStream_t stream)
{
  const float* s    = (const float*)d_in[0];
  const float* z    = (const float*)d_in[1];
  const float* rotv = (const float*)d_in[2];
  const float* mask = (const float*)d_in[3];
  const float* wq   = (const float*)d_in[4];
  const float* bq   = (const float*)d_in[5];
  const float* wkv  = (const float*)d_in[6];
  const float* bkv  = (const float*)d_in[7];
  const float* wkvp = (const float*)d_in[8];
  const float* bkvp = (const float*)d_in[9];
  const float* wb   = (const float*)d_in[10];
  const float* bb   = (const float*)d_in[11];
  const float* wdz  = (const float*)d_in[12];
  const float* bdz  = (const float*)d_in[13];
  const float* wout = (const float*)d_in[14];
  const float* bout = (const float*)d_in[15];
  const float* lfa  = (const float*)d_in[16];
  const float* gwts = (const float*)d_in[17];
  const float* fwts = (const float*)d_in[18];
  float* out = (float*)d_out;
  float* ws  = (float*)d_ws;

  float* proj  = ws + OFF_PROJ;
  float* Qw    = ws + OFF_QW;
  float* Kst   = ws + OFF_KST;
  float* Vcat  = ws + OFF_VCAT;
  float* A     = ws + OFF_A;     // biasS, overwritten in-place by softmax probs
  float* feats = ws + OFF_FEATS;
  float* part  = ws + OFF_PART;

  proj_kernel     <<<dim3(26, 16), 256, 0, stream>>>(s, wq, bq, wkv, bkv, wkvp, bkvp, proj);
  node_kernel     <<<dim3(512),    128, 0, stream>>>(proj, rotv, lfa, gwts, fwts, Qw, Kst, Vcat);
  zbias_kernel    <<<dim3(2, 512), 256, 0, stream>>>(z, wb, bb, A);
  scores_kernel   <<<dim3(64, 8),  256, 0, stream>>>(Qw, Kst, mask, A);
  yopair_kernel   <<<dim3(512),    256, 0, stream>>>(A, z, wdz, bdz, feats);
  ovgemm_kernel   <<<dim3(32, 8),  256, 0, stream>>>(A, Vcat, feats);
  outgemm_kernel  <<<dim3(6, 8, 8),256, 0, stream>>>(feats, wout, part);
  outreduce_kernel<<<dim3(192),    256, 0, stream>>>(part, bout, out);
}

// Round 5
// 391.050 us; speedup vs baseline: 1.0834x; 1.0010x over previous
//
#include <hip/hip_runtime.h>
#include <hip/hip_bf16.h>
#include <math.h>

// Problem constants (B=1)
// N=512, CS=384, CZ=128, G=16, CH=48, H=8, PQ=8, PV=12, NF=4, CZ4=32
// feats dim = 384 (o) + 96*3 (o_pt xyz) + 96 (norm) + 256 (o_pair) = 1024

// ---- workspace layout (floats) ----
#define OFF_PROJ 0
#define SZ_PROJ (512*1632)
#define OFF_QW (OFF_PROJ + SZ_PROJ)
#define SZ_QW (8*512*192)
#define OFF_KST (OFF_QW + SZ_QW)
#define OFF_VCAT (OFF_KST + SZ_QW)
#define SZ_VCAT (512*768)
#define OFF_A (OFF_VCAT + SZ_VCAT)
#define SZ_A (8*512*512)
#define OFF_PZ (OFF_A + SZ_A)
#define SZ_PZ (512*512*32/2)          // bf16 (ushort), counted in floats
#define OFF_FEATS (OFF_PZ + SZ_PZ)
#define SZ_FEATS (512*1024)
#define OFF_PART (OFF_FEATS + SZ_FEATS)
#define SZ_PART (8*512*384)

// ============ K1: s @ [wq|wkv|wkvp] + bias -> proj (512 x 1632) ============
__global__ __launch_bounds__(256) void proj_kernel(
    const float* __restrict__ s, const float* __restrict__ wq, const float* __restrict__ bq,
    const float* __restrict__ wkv, const float* __restrict__ bkv,
    const float* __restrict__ wkvp, const float* __restrict__ bkvp,
    float* __restrict__ proj)
{
  __shared__ float sT[384][34];
  int ct = blockIdx.x;          // 26 col tiles of 64
  int i0 = blockIdx.y * 32;
  int col0 = ct * 64;
  const float* W; const float* bias; int wld, wcol0;
  if (col0 < 384)       { W = wq;   bias = bq;   wld = 384; wcol0 = col0; }
  else if (col0 < 1152) { W = wkv;  bias = bkv;  wld = 768; wcol0 = col0 - 384; }
  else                  { W = wkvp; bias = bkvp; wld = 480; wcol0 = col0 - 1152; }
  int t = threadIdx.x;
  #pragma unroll
  for (int r = 0; r < 12; r++){
    int e = t + 256*r;
    int i = e & 31;
    int k4 = e >> 5;            // 0..95
    float4 v = *(const float4*)(s + (size_t)(i0 + i)*384 + k4*4);
    sT[k4*4+0][i] = v.x; sT[k4*4+1][i] = v.y; sT[k4*4+2][i] = v.z; sT[k4*4+3][i] = v.w;
  }
  __syncthreads();
  int cr = t & 15;
  int ipair = t >> 4;
  int ii = ipair * 2;
  int wc = wcol0 + cr*4;
  bool valid = (wc + 4 <= wld);
  int wcc = valid ? wc : (wld - 4);
  float acc[2][4];
  #pragma unroll
  for (int q = 0; q < 2; q++)
    #pragma unroll
    for (int p = 0; p < 4; p++) acc[q][p] = 0.f;
  #pragma unroll 4
  for (int k = 0; k < 384; k++){
    float2 a2 = *(const float2*)&sT[k][ii];
    float4 w4 = *(const float4*)(W + (size_t)k*wld + wcc);
    acc[0][0] = fmaf(a2.x, w4.x, acc[0][0]);
    acc[0][1] = fmaf(a2.x, w4.y, acc[0][1]);
    acc[0][2] = fmaf(a2.x, w4.z, acc[0][2]);
    acc[0][3] = fmaf(a2.x, w4.w, acc[0][3]);
    acc[1][0] = fmaf(a2.y, w4.x, acc[1][0]);
    acc[1][1] = fmaf(a2.y, w4.y, acc[1][1]);
    acc[1][2] = fmaf(a2.y, w4.z, acc[1][2]);
    acc[1][3] = fmaf(a2.y, w4.w, acc[1][3]);
  }
  if (valid){
    float4 bv = *(const float4*)(bias + wc);
    #pragma unroll
    for (int q = 0; q < 2; q++){
      int row = i0 + ii + q;
      float4 o;
      o.x = acc[q][0] + bv.x; o.y = acc[q][1] + bv.y;
      o.z = acc[q][2] + bv.z; o.w = acc[q][3] + bv.w;
      *(float4*)(proj + (size_t)row*1632 + col0 + cr*4) = o;
    }
  }
}

// ============ K2: per-node rotation + pack Qw/Kst (192-d), Vcat [j][h][96] ============
__global__ __launch_bounds__(128) void node_kernel(
    const float* __restrict__ proj, const float* __restrict__ rotvec,
    const float* __restrict__ lfa, const float* __restrict__ gwts, const float* __restrict__ fwts,
    float* __restrict__ Qw, float* __restrict__ Kst, float* __restrict__ Vcat)
{
  int i = blockIdx.x, t = threadIdx.x;
  const float* pr = proj + (size_t)i*1632;
  float rx = rotvec[i*3], ry = rotvec[i*3+1], rz = rotvec[i*3+2];
  float nrm = sqrtf(rx*rx + ry*ry + rz*rz);
  float angle = nrm + 1e-8f;
  float inv = 1.0f / fmaxf(nrm, 1e-12f);
  float ax = rx*inv, ay = ry*inv, az = rz*inv;
  float f0 = fwts[0], f1 = fwts[1], f2 = fwts[2], f3 = fwts[3];
  float mfw = fmaxf(fmaxf(f0,f1), fmaxf(f2,f3));
  float e0 = expf(f0-mfw), e1 = expf(f1-mfw), e2 = expf(f2-mfw), e3 = expf(f3-mfw);
  float esum = e0+e1+e2+e3;
  float fw[4] = {e0/esum, e1/esum, e2/esum, e3/esum};
  float fq[4] = { 1.0f*expf(lfa[0]), 0.35355339059327373f*expf(lfa[1]),
                  0.125f*expf(lfa[2]), 0.04419417382415922f*expf(lfa[3]) };
  int h = t >> 4, g = t & 15;
  float gw = log1pf(expf(gwts[g])) * 0.25f;
  float q0 = pr[h*48 + g*3 + 0], q1 = pr[h*48 + g*3 + 1], q2 = pr[h*48 + g*3 + 2];
  float k0 = pr[384 + h*96 + g*3 + 0], k1 = pr[384 + h*96 + g*3 + 1], k2 = pr[384 + h*96 + g*3 + 2];
  #pragma unroll
  for (int f = 0; f < 4; f++){
    float th = angle * fq[f];
    float sn = sinf(th), cs = cosf(th), omc = 1.0f - cs;
    float r00 = cs + omc*ax*ax,       r01 = omc*ax*ay - sn*az,  r02 = omc*ax*az + sn*ay;
    float r10 = omc*ay*ax + sn*az,    r11 = cs + omc*ay*ay,     r12 = omc*ay*az - sn*ax;
    float r20 = omc*az*ax - sn*ay,    r21 = omc*az*ay + sn*ax,  r22 = cs + omc*az*az;
    float qr0 = r00*q0 + r01*q1 + r02*q2;
    float qr1 = r10*q0 + r11*q1 + r12*q2;
    float qr2 = r20*q0 + r21*q1 + r22*q2;
    float kr0 = r00*k0 + r01*k1 + r02*k2;
    float kr1 = r10*k0 + r11*k1 + r12*k2;
    float kr2 = r20*k0 + r21*k1 + r22*k2;
    float sc = fw[f] * gw * 0.57735026918962576f;
    int base = (h*512 + i)*192 + (g*4 + f)*3;
    Qw[base+0] = qr0*sc; Qw[base+1] = qr1*sc; Qw[base+2] = qr2*sc;
    Kst[base+0] = kr0;   Kst[base+1] = kr1;   Kst[base+2] = kr2;
  }
  for (int c = t; c < 384; c += 128){
    int hh = c / 48, cc = c % 48;
    Vcat[(size_t)i*768 + hh*96 + cc] = pr[384 + hh*96 + 48 + cc];
  }
  for (int e = t; e < 288; e += 128){
    int hh = e / 36, r = e % 36;
    int p = r / 3, axv = r % 3;
    Vcat[(size_t)i*768 + hh*96 + 48 + p*3 + axv] = pr[1152 + axv*160 + hh*20 + 8 + p];
  }
}

// ============ K3: z -> biasS (8 ch, sqrt(1/3) folded) + PZ bf16 [i][c][j] (32 ch) ============
// z read ONCE. 128-j blocks, grid (4, 512); conflict-free interleaved LDS planes.
#define ZPLANE 584
__global__ __launch_bounds__(256) void zbias_pz_kernel(
    const float* __restrict__ z, const float* __restrict__ wb, const float* __restrict__ bb,
    const float* __restrict__ wdz, const float* __restrict__ bdz,
    float* __restrict__ biasS, ushort* __restrict__ PZ)
{
  __shared__ float zs[8*ZPLANE];     // 18.7 KB
  __shared__ float Wl[40*132];       // 21.1 KB  -> total 39.8 KB = 4 blocks/CU
  int i = blockIdx.y;
  int jt = blockIdx.x;               // j base = jt*128
  int t = threadIdx.x;
  for (int e = t; e < 40*128; e += 256){
    int ch = e % 40, k = e / 40;
    Wl[ch*132 + k] = (ch < 8) ? wb[k*8 + ch] : wdz[k*32 + (ch - 8)];
  }
  int cg = t >> 6, jg = t & 63;
  int ch0 = cg*10;
  float acc[10][2];
  #pragma unroll
  for (int cc = 0; cc < 10; cc++){ acc[cc][0] = 0.f; acc[cc][1] = 0.f; }
  const float* zrow = z + ((size_t)i*512 + jt*128)*128;
  int a0 = jg*4 + (jg>>3)*4;
  int j1 = 64 + jg;
  int a1 = j1*4 + (j1>>3)*4;
  for (int kt = 0; kt < 4; kt++){
    __syncthreads();
    #pragma unroll
    for (int r = 0; r < 4; r++){
      int idx = t + 256*r;           // 1024 = 128 j * 8 kq
      int kq = idx & 7, j = idx >> 3;
      float4 v = *(const float4*)(zrow + (size_t)j*128 + kt*32 + kq*4);
      *(float4*)&zs[kq*ZPLANE + j*4 + (j>>3)*4] = v;
    }
    __syncthreads();
    #pragma unroll
    for (int kq = 0; kq < 8; kq++){
      float4 z0 = *(const float4*)&zs[kq*ZPLANE + a0];
      float4 z1 = *(const float4*)&zs[kq*ZPLANE + a1];
      #pragma unroll
      for (int cc = 0; cc < 10; cc++){
        float4 w = *(const float4*)&Wl[(ch0+cc)*132 + kt*32 + kq*4];
        acc[cc][0] = fmaf(z0.x, w.x, acc[cc][0]);
        acc[cc][0] = fmaf(z0.y, w.y, acc[cc][0]);
        acc[cc][0] = fmaf(z0.z, w.z, acc[cc][0]);
        acc[cc][0] = fmaf(z0.w, w.w, acc[cc][0]);
        acc[cc][1] = fmaf(z1.x, w.x, acc[cc][1]);
        acc[cc][1] = fmaf(z1.y, w.y, acc[cc][1]);
        acc[cc][1] = fmaf(z1.z, w.z, acc[cc][1]);
        acc[cc][1] = fmaf(z1.w, w.w, acc[cc][1]);
      }
    }
  }
  #pragma unroll
  for (int cc = 0; cc < 10; cc++){
    int ch = ch0 + cc;
    if (ch < 8){
      float b = bb[ch];
      float* bp = biasS + (size_t)ch*262144 + i*512 + jt*128 + jg;
      bp[0]  = 0.57735026918962576f * (acc[cc][0] + b);
      bp[64] = 0.57735026918962576f * (acc[cc][1] + b);
    } else {
      int c = ch - 8;
      float b = bdz[c];
      ushort* pp = PZ + ((size_t)i*32 + c)*512 + jt*128 + jg;
      __hip_bfloat16 v0 = __float2bfloat16(acc[cc][0] + b);
      __hip_bfloat16 v1 = __float2bfloat16(acc[cc][1] + b);
      pp[0]  = *(ushort*)&v0;
      pp[64] = *(ushort*)&v1;
    }
  }
}

// ============ K4: scores + softmax, in-place over biasS -> a ============
// i-tile 8, grid (64, 8) -> 2 blocks/CU. Interleaved Ks planes (conflict-free).
#define KPLANE 2312
__global__ __launch_bounds__(256) void scores_kernel(
    const float* __restrict__ Qw, const float* __restrict__ Kst,
    const float* __restrict__ mask, float* A)
{
  __shared__ float Ks[4*KPLANE];  // 37 KB
  __shared__ float Qs[4*40];
  int i0 = blockIdx.x * 8;
  int h = blockIdx.y;
  int t = threadIdx.x;
  int ig = t >> 6, jl = t & 63;
  const float* Kb = Kst + (size_t)h*512*192;
  const float* Qb = Qw + (size_t)(h*512 + i0)*192;
  float acc[2][8];
  float mj[8];
  #pragma unroll
  for (int jt = 0; jt < 8; jt++) mj[jt] = mask[jt*64 + jl];
  #pragma unroll
  for (int q = 0; q < 2; q++){
    int i = i0 + ig*2 + q;
    float mi = mask[i];
    #pragma unroll
    for (int jt = 0; jt < 8; jt++){
      acc[q][jt] = A[((size_t)h*512 + i)*512 + jt*64 + jl] + 100000.0f*(mi*mj[jt] - 1.0f);
    }
  }
  int ja[8];
  #pragma unroll
  for (int jt = 0; jt < 8; jt++){
    int j = jt*64 + jl;
    ja[jt] = j*4 + (j>>3)*4;
  }
  for (int kc = 0; kc < 12; kc++){
    __syncthreads();
    {
      int k4 = t >> 6;
      #pragma unroll
      for (int r = 0; r < 8; r++){
        int j = (t & 63) + 64*r;
        float4 v = *(const float4*)(Kb + (size_t)j*192 + kc*16 + k4*4);
        *(float4*)&Ks[k4*KPLANE + j*4 + (j>>3)*4] = v;
      }
    }
    if (t < 32){
      int qi = t >> 2, k4 = t & 3;
      float4 v = *(const float4*)(Qb + (size_t)qi*192 + kc*16 + k4*4);
      *(float4*)&Qs[k4*40 + qi*4] = v;
    }
    __syncthreads();
    #pragma unroll
    for (int k4 = 0; k4 < 4; k4++){
      float4 qf[2];
      #pragma unroll
      for (int q = 0; q < 2; q++)
        qf[q] = *(const float4*)&Qs[k4*40 + (ig*2+q)*4];
      #pragma unroll
      for (int jt = 0; jt < 8; jt++){
        float4 kf = *(const float4*)&Ks[k4*KPLANE + ja[jt]];
        #pragma unroll
        for (int q = 0; q < 2; q++){
          acc[q][jt] = fmaf(qf[q].x, kf.x, acc[q][jt]);
          acc[q][jt] = fmaf(qf[q].y, kf.y, acc[q][jt]);
          acc[q][jt] = fmaf(qf[q].z, kf.z, acc[q][jt]);
          acc[q][jt] = fmaf(qf[q].w, kf.w, acc[q][jt]);
        }
      }
    }
  }
  #pragma unroll
  for (int q = 0; q < 2; q++){
    int i = i0 + ig*2 + q;
    float m = acc[q][0];
    #pragma unroll
    for (int jt = 1; jt < 8; jt++) m = fmaxf(m, acc[q][jt]);
    for (int off = 32; off > 0; off >>= 1) m = fmaxf(m, __shfl_xor(m, off));
    float ssum = 0.f;
    #pragma unroll
    for (int jt = 0; jt < 8; jt++){ acc[q][jt] = expf(acc[q][jt] - m); ssum += acc[q][jt]; }
    for (int off = 32; off > 0; off >>= 1) ssum += __shfl_xor(ssum, off);
    float invs = 1.0f / ssum;
    #pragma unroll
    for (int jt = 0; jt < 8; jt++){
      A[((size_t)h*512 + i)*512 + jt*64 + jl] = acc[q][jt] * invs;
    }
  }
}

// ============ K5a: o_pair[i,h,c] = sum_j a[h,i,j] * PZ_bf16[i,c,j] -> feats[768..1024) ============
__global__ __launch_bounds__(256) void opair_kernel(
    const float* __restrict__ A, const ushort* __restrict__ PZ,
    float* __restrict__ feats)
{
  __shared__ float a_s[512*10];     // [j][h] pad 10, 20.5 KB
  int i = blockIdx.x;
  int t = threadIdx.x;
  #pragma unroll
  for (int r = 0; r < 4; r++){
    int idx = t + r*256;            // 1024 = 8h * 128 j4
    int h = idx >> 7, j4 = idx & 127;
    float4 v = *(const float4*)(A + ((size_t)h*512 + i)*512 + j4*4);
    a_s[(j4*4+0)*10 + h] = v.x;
    a_s[(j4*4+1)*10 + h] = v.y;
    a_s[(j4*4+2)*10 + h] = v.z;
    a_s[(j4*4+3)*10 + h] = v.w;
  }
  __syncthreads();
  int h = t >> 5, c = t & 31;
  const ushort* pzb = PZ + ((size_t)i*32 + c)*512;
  const float* ap = a_s + h;
  float acc = 0.f;
  #pragma unroll 8
  for (int j4 = 0; j4 < 128; j4++){
    ushort4 p4 = *(const ushort4*)(pzb + j4*4);
    float z0 = __uint_as_float((unsigned)p4.x << 16);
    float z1 = __uint_as_float((unsigned)p4.y << 16);
    float z2 = __uint_as_float((unsigned)p4.z << 16);
    float z3 = __uint_as_float((unsigned)p4.w << 16);
    acc = fmaf(ap[(j4*4+0)*10], z0, acc);
    acc = fmaf(ap[(j4*4+1)*10], z1, acc);
    acc = fmaf(ap[(j4*4+2)*10], z2, acc);
    acc = fmaf(ap[(j4*4+3)*10], z3, acc);
  }
  feats[(size_t)i*1024 + 768 + h*32 + c] = acc;
}

// ============ K5b: per-h GEMM: o + o_pt + norms -> feats[0..768) ============
__global__ __launch_bounds__(256) void ovgemm_kernel(
    const float* __restrict__ A, const float* __restrict__ Vcat,
    float* __restrict__ feats)
{
  __shared__ float A_s[64*18];      // [k][i], 4.6 KB
  __shared__ float V_s[64*100];     // [k][c], 25.6 KB
  __shared__ float opt[16*40];      // o_pt staging for norms
  int i0 = blockIdx.x * 16;
  int h = blockIdx.y;
  int t = threadIdx.x;
  int ip = t >> 5;                  // i-pair index 0..7
  int cg = t & 31;                  // c-quad 0..31 (active < 24)
  float acc[2][4];
  #pragma unroll
  for (int q = 0; q < 2; q++)
    #pragma unroll
    for (int m = 0; m < 4; m++) acc[q][m] = 0.f;
  for (int cb = 0; cb < 512; cb += 64){
    __syncthreads();
    {
      int ii = t >> 4, j4 = t & 15;
      float4 v = *(const float4*)(A + ((size_t)h*512 + i0 + ii)*512 + cb + j4*4);
      A_s[(j4*4+0)*18 + ii] = v.x;
      A_s[(j4*4+1)*18 + ii] = v.y;
      A_s[(j4*4+2)*18 + ii] = v.z;
      A_s[(j4*4+3)*18 + ii] = v.w;
    }
    #pragma unroll
    for (int r = 0; r < 6; r++){
      int idx = t + r*256;          // 1536 = 64 j * 24 cq
      int j = idx / 24, cq = idx % 24;
      float4 v = *(const float4*)(Vcat + (size_t)(cb + j)*768 + h*96 + cq*4);
      *(float4*)&V_s[j*100 + cq*4] = v;
    }
    __syncthreads();
    #pragma unroll 4
    for (int k = 0; k < 64; k++){
      float2 a2 = *(const float2*)&A_s[k*18 + ip*2];
      float4 v4 = *(const float4*)&V_s[k*100 + cg*4];
      acc[0][0] = fmaf(a2.x, v4.x, acc[0][0]);
      acc[0][1] = fmaf(a2.x, v4.y, acc[0][1]);
      acc[0][2] = fmaf(a2.x, v4.z, acc[0][2]);
      acc[0][3] = fmaf(a2.x, v4.w, acc[0][3]);
      acc[1][0] = fmaf(a2.y, v4.x, acc[1][0]);
      acc[1][1] = fmaf(a2.y, v4.y, acc[1][1]);
      acc[1][2] = fmaf(a2.y, v4.z, acc[1][2]);
      acc[1][3] = fmaf(a2.y, v4.w, acc[1][3]);
    }
  }
  int c0 = cg*4;
  if (c0 < 48){
    #pragma unroll
    for (int q = 0; q < 2; q++){
      *(float4*)&feats[(size_t)(i0 + ip*2 + q)*1024 + h*48 + c0] =
        make_float4(acc[q][0], acc[q][1], acc[q][2], acc[q][3]);
    }
  } else if (c0 < 84){
    #pragma unroll
    for (int q = 0; q < 2; q++){
      #pragma unroll
      for (int m = 0; m < 4; m++){
        opt[(ip*2+q)*40 + (c0 - 48 + m)] = acc[q][m];
      }
    }
  }
  __syncthreads();
  if (t < 192){
    int il = t / 12, p = t % 12;
    float x = opt[il*40 + p*3], y = opt[il*40 + p*3 + 1], zz = opt[il*40 + p*3 + 2];
    float* fr = feats + (size_t)(i0 + il)*1024;
    fr[384 + h*12 + p] = x;
    fr[480 + h*12 + p] = y;
    fr[576 + h*12 + p] = zz;
    fr[672 + h*12 + p] = sqrtf(x*x + y*y + zz*zz + 1e-8f);
  }
}

// ============ K6: out = feats @ wout (+bout in reduce); split-K=8 partials ============
__global__ __launch_bounds__(256) void outgemm_kernel(
    const float* __restrict__ feats, const float* __restrict__ wout,
    float* __restrict__ part)
{
  __shared__ float fA[32*68];
  __shared__ float fB[32*68];
  int ct = blockIdx.x;
  int it = blockIdx.y;
  int sk = blockIdx.z;
  int i0 = it*64, c0 = ct*64, k0 = sk*128;
  int t = threadIdx.x;
  int ir = t >> 4, cr = t & 15;
  float acc[4][4];
  #pragma unroll
  for (int q = 0; q < 4; q++)
    #pragma unroll
    for (int p = 0; p < 4; p++) acc[q][p] = 0.f;
  for (int kt = 0; kt < 128; kt += 32){
    __syncthreads();
    #pragma unroll
    for (int r = 0; r < 2; r++){
      int e = t + 256*r;
      int i = e & 63, kq = e >> 6;
      float4 v = *(const float4*)(feats + (size_t)(i0 + i)*1024 + k0 + kt + kq*4);
      fA[(kq*4+0)*68 + i] = v.x; fA[(kq*4+1)*68 + i] = v.y;
      fA[(kq*4+2)*68 + i] = v.z; fA[(kq*4+3)*68 + i] = v.w;
    }
    #pragma unroll
    for (int r = 0; r < 2; r++){
      int e = t + 256*r;
      int kk = e >> 4, c4 = e & 15;
      float4 v = *(const float4*)(wout + (size_t)(k0 + kt + kk)*384 + c0 + c4*4);
      *(float4*)&fB[kk*68 + c4*4] = v;
    }
    __syncthreads();
    #pragma unroll 8
    for (int k = 0; k < 32; k++){
      float4 a4 = *(const float4*)&fA[k*68 + ir*4];
      float4 b4 = *(const float4*)&fB[k*68 + cr*4];
      acc[0][0] = fmaf(a4.x, b4.x, acc[0][0]);
      acc[0][1] = fmaf(a4.x, b4.y, acc[0][1]);
      acc[0][2] = fmaf(a4.x, b4.z, acc[0][2]);
      acc[0][3] = fmaf(a4.x, b4.w, acc[0][3]);
      acc[1][0] = fmaf(a4.y, b4.x, acc[1][0]);
      acc[1][1] = fmaf(a4.y, b4.y, acc[1][1]);
      acc[1][2] = fmaf(a4.y, b4.z, acc[1][2]);
      acc[1][3] = fmaf(a4.y, b4.w, acc[1][3]);
      acc[2][0] = fmaf(a4.z, b4.x, acc[2][0]);
      acc[2][1] = fmaf(a4.z, b4.y, acc[2][1]);
      acc[2][2] = fmaf(a4.z, b4.z, acc[2][2]);
      acc[2][3] = fmaf(a4.z, b4.w, acc[2][3]);
      acc[3][0] = fmaf(a4.w, b4.x, acc[3][0]);
      acc[3][1] = fmaf(a4.w, b4.y, acc[3][1]);
      acc[3][2] = fmaf(a4.w, b4.z, acc[3][2]);
      acc[3][3] = fmaf(a4.w, b4.w, acc[3][3]);
    }
  }
  float* pb = part + ((size_t)sk*512 + i0)*384 + c0;
  #pragma unroll
  for (int q = 0; q < 4; q++){
    float4 o;
    o.x = acc[q][0]; o.y = acc[q][1]; o.z = acc[q][2]; o.w = acc[q][3];
    *(float4*)&pb[(size_t)(ir*4 + q)*384 + cr*4] = o;
  }
}

__global__ __launch_bounds__(256) void outreduce_kernel(
    const float* __restrict__ part, const float* __restrict__ bout,
    float* __restrict__ out)
{
  int e = blockIdx.x*256 + threadIdx.x;
  float4 acc = *(const float4*)(bout + (e % 96)*4);
  #pragma unroll
  for (int sk = 0; sk < 8; sk++){
    float4 p = *(const float4*)(part + (size_t)sk*196608 + (size_t)e*4);
    acc.x += p.x; acc.y += p.y; acc.z += p.z; acc.w += p.w;
  }
  *(float4*)(out + (size_t)e*4) = acc;
}

extern "C" void kernel_launch(void* const* d_in, const int* in_sizes, int n_in,
                              void* d_out, int out_size, void* d_ws, size_t ws_size,
                              hipStream_t stream)
{
  const float* s    = (const float*)d_in[0];
  const float* z    = (const float*)d_in[1];
  const float* rotv = (const float*)d_in[2];
  const float* mask = (const float*)d_in[3];
  const float* wq   = (const float*)d_in[4];
  const float* bq   = (const float*)d_in[5];
  const float* wkv  = (const float*)d_in[6];
  const float* bkv  = (const float*)d_in[7];
  const float* wkvp = (const float*)d_in[8];
  const float* bkvp = (const float*)d_in[9];
  const float* wb   = (const float*)d_in[10];
  const float* bb   = (const float*)d_in[11];
  const float* wdz  = (const float*)d_in[12];
  const float* bdz  = (const float*)d_in[13];
  const float* wout = (const float*)d_in[14];
  const float* bout = (const float*)d_in[15];
  const float* lfa  = (const float*)d_in[16];
  const float* gwts = (const float*)d_in[17];
  const float* fwts = (const float*)d_in[18];
  float* out = (float*)d_out;
  float* ws  = (float*)d_ws;

  float* proj  = ws + OFF_PROJ;
  float* Qw    = ws + OFF_QW;
  float* Kst   = ws + OFF_KST;
  float* Vcat  = ws + OFF_VCAT;
  float* A     = ws + OFF_A;     // biasS, overwritten in-place by softmax probs
  ushort* PZ   = (ushort*)(ws + OFF_PZ);
  float* feats = ws + OFF_FEATS;
  float* part  = ws + OFF_PART;

  proj_kernel     <<<dim3(26, 16), 256, 0, stream>>>(s, wq, bq, wkv, bkv, wkvp, bkvp, proj);
  node_kernel     <<<dim3(512),    128, 0, stream>>>(proj, rotv, lfa, gwts, fwts, Qw, Kst, Vcat);
  zbias_pz_kernel <<<dim3(4, 512), 256, 0, stream>>>(z, wb, bb, wdz, bdz, A, PZ);
  scores_kernel   <<<dim3(64, 8),  256, 0, stream>>>(Qw, Kst, mask, A);
  opair_kernel    <<<dim3(512),    256, 0, stream>>>(A, PZ, feats);
  ovgemm_kernel   <<<dim3(32, 8),  256, 0, stream>>>(A, Vcat, feats);
  outgemm_kernel  <<<dim3(6, 8, 8),256, 0, stream>>>(feats, wout, part);
  outreduce_kernel<<<dim3(192),    256, 0, stream>>>(part, bout, out);
}